// Round 1
// 1041.652 us; speedup vs baseline: 1.1166x; 1.1166x over previous
//
#include <hip/hip_runtime.h>

// Problem: FastformerAttention  B=32, N=4096, DIM=512, DD=512
//
// R3 pipeline (v eliminated algebraically):
//   out = (gk ⊙ v)·Wr + q = x·(Wv·diag(gk)·Wr + Wq) = x·Wfin_b
//
//   convert_x : xb[131072][512] = bf16(x)                (ws)
//   prep_w    : Wt[1024][512] = bf16([Wq|Wk]^T); Wrt[512][512] = bf16(Wr^T)
//   gemm_qk   : qk[131072][1024] bf16 = xb @ Wt^T        (XCD-chunk swizzled)
//   pool_alpha: gq[b][512] = sum_n q*softmax_d(q*alpha*SCALE)
//   pool_beta : gk[b][512] = sum_n p*softmax_d(p*beta*SCALE), p = gq⊙k
//   build_vgk : Vgk[b][i][d] = bf16(Wv[i][d]*gk[b][d])   (coalesced)
//   gemm_wfin : Wfin_b[e][i] = Wrt @ Vgk_b^T + Wq^T      (bf16, B^T layout)
//   gemm_final: out[b][n][e] = xb_b @ Wfin_b^T           (fp32 out)

typedef __attribute__((ext_vector_type(8))) short short8;
typedef __attribute__((ext_vector_type(4))) float floatx4;
typedef unsigned short u16;
typedef unsigned int u32;

#define SEQ 4096
#define BATCH 32
#define NQK 1024
#define FSCALE 0.044194173824159216f  // 512^-0.5

__device__ __forceinline__ u16 f2bf(float f) {
  u32 u = __float_as_uint(f);
  u += 0x7fffu + ((u >> 16) & 1u);  // RNE
  return (u16)(u >> 16);
}
__device__ __forceinline__ float bf2f(u16 h) { return __uint_as_float((u32)h << 16); }

__device__ __forceinline__ void g2l16(const void* g, void* l) {
  __builtin_amdgcn_global_load_lds(
      (const __attribute__((address_space(1))) void*)g,
      (__attribute__((address_space(3))) void*)l, 16, 0, 0);
}

// ---------------- convert x: fp32 -> bf16 ----------------
__global__ __launch_bounds__(256) void convert_x(const float* __restrict__ x,
                                                 u16* __restrict__ xb) {
  size_t i = ((size_t)blockIdx.x * 256 + threadIdx.x) * 8;
  float4 f0 = *(const float4*)(x + i);
  float4 f1 = *(const float4*)(x + i + 4);
  short8 s;
  s[0] = (short)f2bf(f0.x); s[1] = (short)f2bf(f0.y);
  s[2] = (short)f2bf(f0.z); s[3] = (short)f2bf(f0.w);
  s[4] = (short)f2bf(f1.x); s[5] = (short)f2bf(f1.y);
  s[6] = (short)f2bf(f1.z); s[7] = (short)f2bf(f1.w);
  *(short8*)(xb + i) = s;
}

// ---------------- prep: Wt = [Wq|Wk]^T bf16, Wrt = Wr^T bf16 ----------------
__global__ void prep_w(const float* __restrict__ Wq, const float* __restrict__ Wk,
                       const float* __restrict__ Wr, u16* __restrict__ Wt,
                       u16* __restrict__ Wrt) {
  int n = blockIdx.x;  // 0..1535
  if (n < 1024) {
    const float* W = (n < 512) ? Wq : Wk;
    int col = n & 511;
    for (int kk = threadIdx.x; kk < 512; kk += 256)
      Wt[(size_t)n * 512 + kk] = f2bf(W[(size_t)kk * 512 + col]);
  } else {
    int e = n - 1024;
    for (int d = threadIdx.x; d < 512; d += 256)
      Wrt[(size_t)e * 512 + d] = f2bf(Wr[(size_t)d * 512 + e]);
  }
}

// ---------------- shared 128x128 MFMA tile core (m97 structure) ----------------
template <int LDA, int LDB, int KTILES>
__device__ __forceinline__ void gemm_core(const u16* __restrict__ A,
                                          const u16* __restrict__ B,
                                          int row0, int col0,
                                          u16* sA, u16* sB,
                                          floatx4 (&acc)[4][4]) {
  const int tid = threadIdx.x;
  const int lane = tid & 63, wv = tid >> 6;
  const int wm = (wv >> 1) * 64, wn = (wv & 1) * 64;
  const int ln = lane & 15;
  const int quad = lane >> 4;
  const int b_row = lane >> 2;
  const int b_kq = (lane & 3) * 8;

  for (int kt = 0; kt < KTILES; ++kt) {
    const int k0 = kt * 32;
    __syncthreads();
#pragma unroll
    for (int c = 0; c < 2; ++c) {
      int chunk = wv * 2 + c;
      int r = chunk * 16 + b_row;
      g2l16(A + (size_t)(row0 + r) * LDA + k0 + b_kq, sA + chunk * 512 + lane * 8);
      g2l16(B + (size_t)(col0 + r) * LDB + k0 + b_kq, sB + chunk * 512 + lane * 8);
    }
    __syncthreads();

    short8 a[4], b[4];
#pragma unroll
    for (int i = 0; i < 4; ++i)
      a[i] = *(const short8*)&sA[(wm + i * 16 + ln) * 32 + quad * 8];
#pragma unroll
    for (int j = 0; j < 4; ++j)
      b[j] = *(const short8*)&sB[(wn + j * 16 + ln) * 32 + quad * 8];
#pragma unroll
    for (int i = 0; i < 4; ++i)
#pragma unroll
      for (int j = 0; j < 4; ++j)
        acc[i][j] = __builtin_amdgcn_mfma_f32_16x16x32_bf16(a[i], b[j], acc[i][j], 0, 0, 0);
  }
}

// ---------------- GEMM: qk = xb @ Wt^T (bf16 out), XCD-chunk swizzled ----------------
__global__ __launch_bounds__(256) void gemm_qk(const u16* __restrict__ xb,
                                               const u16* __restrict__ Wt,
                                               u16* __restrict__ qk) {
  __shared__ u16 sA[128 * 32];
  __shared__ u16 sB[128 * 32];
  // nwg = 8*1024 = 8192, divisible by 8 -> bijective chunked swizzle.
  int bid = blockIdx.y * 8 + blockIdx.x;
  int swz = (bid & 7) * 1024 + (bid >> 3);
  const int row0 = (swz >> 3) * 128;  // M tile (131072 rows)
  const int col0 = (swz & 7) * 128;   // N tile (1024 cols)

  floatx4 acc[4][4] = {};
  gemm_core<512, 512, 16>(xb, Wt, row0, col0, sA, sB, acc);

  const int lane = threadIdx.x & 63, wv = threadIdx.x >> 6;
  const int wm = (wv >> 1) * 64, wn = (wv & 1) * 64;
  const int ln = lane & 15, quad = lane >> 4;
#pragma unroll
  for (int i = 0; i < 4; ++i) {
#pragma unroll
    for (int r = 0; r < 4; ++r) {
      int grow = row0 + wm + i * 16 + quad * 4 + r;
      size_t base = (size_t)grow * NQK + col0 + wn + ln;
#pragma unroll
      for (int j = 0; j < 4; ++j) qk[base + j * 16] = f2bf(acc[i][j][r]);
    }
  }
}

// ---------------- pools: per-row softmax over d, sum over n ----------------
__global__ __launch_bounds__(256) void pool_alpha(const u16* __restrict__ qk,
                                                  const float* __restrict__ alpha,
                                                  float* __restrict__ gq) {
  const int b = blockIdx.y;
  const int lane = threadIdx.x & 63, wv = threadIdx.x >> 6;
  const int slot = blockIdx.x * 4 + wv;  // 0..63
  float a8[8], acc8[8];
#pragma unroll
  for (int j = 0; j < 8; ++j) {
    a8[j] = alpha[lane * 8 + j] * FSCALE;
    acc8[j] = 0.f;
  }
  for (int i = 0; i < 64; ++i) {
    int row = slot * 64 + i;
    const u16* qr = qk + (size_t)(b * SEQ + row) * NQK + lane * 8;
    short8 s = *(const short8*)qr;
    float q[8], t[8];
    float m = -1e30f;
#pragma unroll
    for (int j = 0; j < 8; ++j) {
      q[j] = bf2f((u16)s[j]);
      t[j] = q[j] * a8[j];
      m = fmaxf(m, t[j]);
    }
#pragma unroll
    for (int off = 32; off >= 1; off >>= 1) m = fmaxf(m, __shfl_xor(m, off));
    float sum = 0.f;
    float e[8];
#pragma unroll
    for (int j = 0; j < 8; ++j) {
      e[j] = __expf(t[j] - m);
      sum += e[j];
    }
#pragma unroll
    for (int off = 32; off >= 1; off >>= 1) sum += __shfl_xor(sum, off);
    float inv = 1.f / sum;
#pragma unroll
    for (int j = 0; j < 8; ++j) acc8[j] += q[j] * e[j] * inv;
  }
#pragma unroll
  for (int j = 0; j < 8; ++j) atomicAdd(&gq[b * 512 + lane * 8 + j], acc8[j]);
}

__global__ __launch_bounds__(256) void pool_beta(const u16* __restrict__ qk,
                                                 const float* __restrict__ beta,
                                                 const float* __restrict__ gq,
                                                 float* __restrict__ gk) {
  const int b = blockIdx.y;
  const int lane = threadIdx.x & 63, wv = threadIdx.x >> 6;
  const int slot = blockIdx.x * 4 + wv;
  float b8[8], g8[8], acc8[8];
#pragma unroll
  for (int j = 0; j < 8; ++j) {
    b8[j] = beta[lane * 8 + j] * FSCALE;
    g8[j] = gq[b * 512 + lane * 8 + j];
    acc8[j] = 0.f;
  }
  for (int i = 0; i < 64; ++i) {
    int row = slot * 64 + i;
    const u16* kr = qk + (size_t)(b * SEQ + row) * NQK + 512 + lane * 8;
    short8 s = *(const short8*)kr;
    float p[8], t[8];
    float m = -1e30f;
#pragma unroll
    for (int j = 0; j < 8; ++j) {
      p[j] = g8[j] * bf2f((u16)s[j]);
      t[j] = p[j] * b8[j];
      m = fmaxf(m, t[j]);
    }
#pragma unroll
    for (int off = 32; off >= 1; off >>= 1) m = fmaxf(m, __shfl_xor(m, off));
    float sum = 0.f;
    float e[8];
#pragma unroll
    for (int j = 0; j < 8; ++j) {
      e[j] = __expf(t[j] - m);
      sum += e[j];
    }
#pragma unroll
    for (int off = 32; off >= 1; off >>= 1) sum += __shfl_xor(sum, off);
    float inv = 1.f / sum;
#pragma unroll
    for (int j = 0; j < 8; ++j) acc8[j] += p[j] * e[j] * inv;
  }
#pragma unroll
  for (int j = 0; j < 8; ++j) atomicAdd(&gk[b * 512 + lane * 8 + j], acc8[j]);
}

// ---------------- Vgk[b][i][d] = bf16(Wv[i][d] * gk[b][d]) ----------------
__global__ void build_vgk(const float* __restrict__ Wv, const float* __restrict__ gk,
                          u16* __restrict__ Vgk) {
  int i = blockIdx.x, b = blockIdx.y;
  const float* gr = gk + b * 512;
  const float* wr = Wv + (size_t)i * 512;
  u16* o = Vgk + ((size_t)b * 512 + i) * 512;
  for (int d = threadIdx.x; d < 512; d += 256) o[d] = f2bf(wr[d] * gr[d]);
}

// ---------------- Wfin_b[e][i] = (Wrt @ Vgk_b^T)[e][i] + Wq[i][e], bf16 ----------------
__global__ __launch_bounds__(256) void gemm_wfin(const u16* __restrict__ Wrt,
                                                 const u16* __restrict__ Vgk,
                                                 const float* __restrict__ Wq,
                                                 u16* __restrict__ Wfin) {
  __shared__ u16 sA[128 * 32];
  __shared__ u16 sB[128 * 32];
  const int b = blockIdx.z;
  const int row0 = blockIdx.y * 128;  // e
  const int col0 = blockIdx.x * 128;  // i
  const u16* Bb = Vgk + (size_t)b * 512 * 512;
  u16* Cb = Wfin + (size_t)b * 512 * 512;

  floatx4 acc[4][4] = {};
  gemm_core<512, 512, 16>(Wrt, Bb, row0, col0, sA, sB, acc);

  const int lane = threadIdx.x & 63, wv = threadIdx.x >> 6;
  const int wm = (wv >> 1) * 64, wn = (wv & 1) * 64;
  const int ln = lane & 15, quad = lane >> 4;
#pragma unroll
  for (int i = 0; i < 4; ++i) {
#pragma unroll
    for (int r = 0; r < 4; ++r) {
      int grow = row0 + wm + i * 16 + quad * 4 + r;  // e
#pragma unroll
      for (int j = 0; j < 4; ++j) {
        int gcol = col0 + wn + ln + j * 16;  // i
        Cb[(size_t)grow * 512 + gcol] = f2bf(acc[i][j][r] + Wq[(size_t)gcol * 512 + grow]);
      }
    }
  }
}

// ---------------- out_b = xb_b @ Wfin_b^T (fp32 out) ----------------
__global__ __launch_bounds__(256) void gemm_final(const u16* __restrict__ xb,
                                                  const u16* __restrict__ Wfin,
                                                  float* __restrict__ out) {
  __shared__ u16 sA[128 * 32];
  __shared__ u16 sB[128 * 32];
  const int b = blockIdx.z;
  // per-z nwg = 4*32 = 128, divisible by 8 -> bijective chunked swizzle.
  int bid = blockIdx.y * 4 + blockIdx.x;
  int swz = (bid & 7) * 16 + (bid >> 3);
  const int row0 = (swz >> 2) * 128;  // 0..4095
  const int col0 = (swz & 3) * 128;   // 0..511
  const u16* Ab = xb + (size_t)b * SEQ * 512;
  const u16* Bb = Wfin + (size_t)b * 512 * 512;

  floatx4 acc[4][4] = {};
  gemm_core<512, 512, 16>(Ab, Bb, row0, col0, sA, sB, acc);

  const int lane = threadIdx.x & 63, wv = threadIdx.x >> 6;
  const int wm = (wv >> 1) * 64, wn = (wv & 1) * 64;
  const int ln = lane & 15, quad = lane >> 4;
#pragma unroll
  for (int i = 0; i < 4; ++i) {
#pragma unroll
    for (int r = 0; r < 4; ++r) {
      int grow = row0 + wm + i * 16 + quad * 4 + r;
      size_t orow = ((size_t)b * SEQ + grow) * 512;
#pragma unroll
      for (int j = 0; j < 4; ++j) {
        int gcol = col0 + wn + ln + j * 16;
        out[orow + gcol] = acc[i][j][r];
      }
    }
  }
}

// ---------------- launcher ----------------
extern "C" void kernel_launch(void* const* d_in, const int* in_sizes, int n_in,
                              void* d_out, int out_size, void* d_ws, size_t ws_size,
                              hipStream_t stream) {
  const float* x = (const float*)d_in[0];
  const float* Wq = (const float*)d_in[1];
  const float* Wk = (const float*)d_in[2];
  const float* Wv = (const float*)d_in[3];
  const float* Wr = (const float*)d_in[4];
  const float* alpha = (const float*)d_in[5];
  const float* beta = (const float*)d_in[6];
  float* out = (float*)d_out;

  char* ws = (char*)d_ws;
  // ws layout (bytes):
  //   xb   @ 0           134,217,728  (131072 x 512 bf16)
  //   qk   @ 134,217,728 268,435,456  (131072 x 1024 bf16; dead after pool_beta)
  //   Vgk  @ 134,217,728  16,777,216  (aliases dead qk)
  //   Wfin @ 151,994,944  16,777,216  (aliases dead qk)
  //   Wt   @ 402,653,184   1,048,576
  //   Wrt  @ 403,701,760     524,288
  //   gq   @ 404,226,048      65,536
  //   gk   @ 404,291,584      65,536   (total 404,357,120 < previous 421 MB)
  u16* xb = (u16*)ws;
  u16* qk = (u16*)(ws + 134217728ull);
  u16* Vgk = (u16*)(ws + 134217728ull);
  u16* Wfin = (u16*)(ws + 151994944ull);
  u16* Wt = (u16*)(ws + 402653184ull);
  u16* Wrt = (u16*)(ws + 403701760ull);
  float* gq = (float*)(ws + 404226048ull);
  float* gk = gq + 16384;

  hipMemsetAsync(gq, 0, 131072, stream);  // gq+gk
  convert_x<<<32768, 256, 0, stream>>>(x, xb);
  prep_w<<<1536, 256, 0, stream>>>(Wq, Wk, Wr, Wt, Wrt);
  gemm_qk<<<dim3(8, 1024), 256, 0, stream>>>(xb, Wt, qk);
  pool_alpha<<<dim3(16, BATCH), 256, 0, stream>>>(qk, alpha, gq);
  pool_beta<<<dim3(16, BATCH), 256, 0, stream>>>(qk, beta, gq, gk);
  build_vgk<<<dim3(512, BATCH), 256, 0, stream>>>(Wv, gk, Vgk);
  gemm_wfin<<<dim3(4, 4, BATCH), 256, 0, stream>>>(Wrt, Vgk, Wq, Wfin);
  gemm_final<<<dim3(4, 32, BATCH), 256, 0, stream>>>(xb, Wfin, out);
}

// Round 3
// 983.874 us; speedup vs baseline: 1.1822x; 1.0587x over previous
//
#include <hip/hip_runtime.h>

// Problem: FastformerAttention  B=32, N=4096, DIM=512, DD=512
//
// R4 pipeline (same algebra as R3; GEMM core upgraded to 2-phase prefetch dbuf):
//   out = (gk ⊙ v)·Wr + q = x·(Wv·diag(gk)·Wr + Wq) = x·Wfin_b
//
//   convert_x : xb[131072][512] = bf16(x)                (ws)
//   prep_w    : Wt[1024][512] = bf16([Wq|Wk]^T); Wrt[512][512] = bf16(Wr^T)
//   gemm_qk   : qk[131072][1024] bf16 = xb @ Wt^T        (XCD-chunk swizzled)
//   pool_alpha: gq[b][512] = sum_n q*softmax_d(q*alpha*SCALE)
//   pool_beta : gk[b][512] = sum_n p*softmax_d(p*beta*SCALE), p = gq⊙k
//   build_vgk : Vgk[b][i][d] = bf16(Wv[i][d]*gk[b][d])
//   gemm_wfin : Wfin_b[e][i] = Wrt @ Vgk_b^T + Wq^T      (bf16, B^T layout)
//   gemm_final: out[b][n][e] = xb_b @ Wfin_b^T           (fp32 out)
//
// gemm_core is the T3-minimum 2-phase schedule (catalog recipe):
//   prologue: STAGE(buf0, kt=0); barrier
//   loop:     STAGE(buf^1, kt+1); ds_read buf; MFMA; barrier
//   (one barrier per K-step; global-load latency hidden under ds_read+MFMA)

typedef __attribute__((ext_vector_type(8))) short short8;
typedef __attribute__((ext_vector_type(4))) float floatx4;
typedef unsigned short u16;
typedef unsigned int u32;

#define SEQ 4096
#define BATCH 32
#define NQK 1024
#define FSCALE 0.044194173824159216f  // 512^-0.5

__device__ __forceinline__ u16 f2bf(float f) {
  u32 u = __float_as_uint(f);
  u += 0x7fffu + ((u >> 16) & 1u);  // RNE
  return (u16)(u >> 16);
}
__device__ __forceinline__ float bf2f(u16 h) { return __uint_as_float((u32)h << 16); }

__device__ __forceinline__ void g2l16(const void* g, void* l) {
  __builtin_amdgcn_global_load_lds(
      (const __attribute__((address_space(1))) void*)g,
      (__attribute__((address_space(3))) void*)l, 16, 0, 0);
}

// ---------------- convert x: fp32 -> bf16 ----------------
__global__ __launch_bounds__(256) void convert_x(const float* __restrict__ x,
                                                 u16* __restrict__ xb) {
  size_t i = ((size_t)blockIdx.x * 256 + threadIdx.x) * 8;
  float4 f0 = *(const float4*)(x + i);
  float4 f1 = *(const float4*)(x + i + 4);
  short8 s;
  s[0] = (short)f2bf(f0.x); s[1] = (short)f2bf(f0.y);
  s[2] = (short)f2bf(f0.z); s[3] = (short)f2bf(f0.w);
  s[4] = (short)f2bf(f1.x); s[5] = (short)f2bf(f1.y);
  s[6] = (short)f2bf(f1.z); s[7] = (short)f2bf(f1.w);
  *(short8*)(xb + i) = s;
}

// ---------------- prep: Wt = [Wq|Wk]^T bf16, Wrt = Wr^T bf16 ----------------
__global__ void prep_w(const float* __restrict__ Wq, const float* __restrict__ Wk,
                       const float* __restrict__ Wr, u16* __restrict__ Wt,
                       u16* __restrict__ Wrt) {
  int n = blockIdx.x;  // 0..1535
  if (n < 1024) {
    const float* W = (n < 512) ? Wq : Wk;
    int col = n & 511;
    for (int kk = threadIdx.x; kk < 512; kk += 256)
      Wt[(size_t)n * 512 + kk] = f2bf(W[(size_t)kk * 512 + col]);
  } else {
    int e = n - 1024;
    for (int d = threadIdx.x; d < 512; d += 256)
      Wrt[(size_t)e * 512 + d] = f2bf(Wr[(size_t)d * 512 + e]);
  }
}

// ---------------- 128x128 MFMA tile core, 2-phase prefetch double-buffer ----------------
// LDS: caller provides 4 x 8KB buffers (A0,B0,A1,B1). KTILES must be even.
template <int LDA, int LDB, int KTILES>
__device__ __forceinline__ void gemm_core(const u16* __restrict__ A,
                                          const u16* __restrict__ B,
                                          int row0, int col0,
                                          u16* sA0, u16* sB0, u16* sA1, u16* sB1,
                                          floatx4 (&acc)[4][4]) {
  const int tid = threadIdx.x;
  const int lane = tid & 63, wv = tid >> 6;
  const int wm = (wv >> 1) * 64, wn = (wv & 1) * 64;
  const int ln = lane & 15;
  const int quad = lane >> 4;
  const int b_row = lane >> 2;
  const int b_kq = (lane & 3) * 8;

  // per-thread global row bases (constant across K)
  const int chunk0 = wv * 2, chunk1 = wv * 2 + 1;
  const u16* gA0 = A + (size_t)(row0 + chunk0 * 16 + b_row) * LDA + b_kq;
  const u16* gA1 = A + (size_t)(row0 + chunk1 * 16 + b_row) * LDA + b_kq;
  const u16* gB0 = B + (size_t)(col0 + chunk0 * 16 + b_row) * LDB + b_kq;
  const u16* gB1 = B + (size_t)(col0 + chunk1 * 16 + b_row) * LDB + b_kq;
  const int lA0 = chunk0 * 512 + lane * 8;
  const int lA1 = chunk1 * 512 + lane * 8;

#define STAGE_KT(pA, pB, kt)                \
  do {                                      \
    const int k0_ = (kt) * 32;              \
    g2l16(gA0 + k0_, (pA) + lA0);           \
    g2l16(gA1 + k0_, (pA) + lA1);           \
    g2l16(gB0 + k0_, (pB) + lA0);           \
    g2l16(gB1 + k0_, (pB) + lA1);           \
  } while (0)

#define COMPUTE_KT(cA, cB)                                                     \
  do {                                                                         \
    short8 a_[4], b_[4];                                                       \
    _Pragma("unroll") for (int i = 0; i < 4; ++i)                              \
        a_[i] = *(const short8*)&(cA)[(wm + i * 16 + ln) * 32 + quad * 8];     \
    _Pragma("unroll") for (int j = 0; j < 4; ++j)                              \
        b_[j] = *(const short8*)&(cB)[(wn + j * 16 + ln) * 32 + quad * 8];     \
    _Pragma("unroll") for (int i = 0; i < 4; ++i)                              \
        _Pragma("unroll") for (int j = 0; j < 4; ++j)                          \
            acc[i][j] =                                                        \
        __builtin_amdgcn_mfma_f32_16x16x32_bf16(a_[i], b_[j], acc[i][j], 0, 0, 0); \
  } while (0)

  // prologue: stage K-tile 0 into buf0
  STAGE_KT(sA0, sB0, 0);
  __syncthreads();  // implicit vmcnt(0) drain -> buf0 resident

  for (int kt = 0; kt < KTILES; kt += 2) {
    // compute buf0 (tile kt), stage buf1 (tile kt+1) first so latency hides
    STAGE_KT(sA1, sB1, kt + 1);
    COMPUTE_KT(sA0, sB0);
    __syncthreads();  // drains vmcnt -> buf1 resident; buf0 free

    // compute buf1 (tile kt+1), stage buf0 (tile kt+2) unless last pair
    if (kt + 2 < KTILES) {
      STAGE_KT(sA0, sB0, kt + 2);
      COMPUTE_KT(sA1, sB1);
      __syncthreads();  // buf0 resident; buf1 free
    } else {
      COMPUTE_KT(sA1, sB1);
    }
  }
#undef STAGE_KT
#undef COMPUTE_KT
}

// ---------------- GEMM: qk = xb @ Wt^T (bf16 out), XCD-chunk swizzled ----------------
__global__ __launch_bounds__(256) void gemm_qk(const u16* __restrict__ xb,
                                               const u16* __restrict__ Wt,
                                               u16* __restrict__ qk) {
  __shared__ u16 sA0[128 * 32], sB0[128 * 32], sA1[128 * 32], sB1[128 * 32];
  // nwg = 8*1024 = 8192, divisible by 8 -> bijective chunked swizzle.
  int bid = blockIdx.y * 8 + blockIdx.x;
  int swz = (bid & 7) * 1024 + (bid >> 3);
  const int row0 = (swz >> 3) * 128;  // M tile (131072 rows)
  const int col0 = (swz & 7) * 128;   // N tile (1024 cols)

  floatx4 acc[4][4] = {};
  gemm_core<512, 512, 16>(xb, Wt, row0, col0, sA0, sB0, sA1, sB1, acc);

  const int lane = threadIdx.x & 63, wv = threadIdx.x >> 6;
  const int wm = (wv >> 1) * 64, wn = (wv & 1) * 64;
  const int ln = lane & 15, quad = lane >> 4;
#pragma unroll
  for (int i = 0; i < 4; ++i) {
#pragma unroll
    for (int r = 0; r < 4; ++r) {
      int grow = row0 + wm + i * 16 + quad * 4 + r;
      size_t base = (size_t)grow * NQK + col0 + wn + ln;
#pragma unroll
      for (int j = 0; j < 4; ++j) qk[base + j * 16] = f2bf(acc[i][j][r]);
    }
  }
}

// ---------------- pools: per-row softmax over d, sum over n ----------------
__global__ __launch_bounds__(256) void pool_alpha(const u16* __restrict__ qk,
                                                  const float* __restrict__ alpha,
                                                  float* __restrict__ gq) {
  const int b = blockIdx.y;
  const int lane = threadIdx.x & 63, wv = threadIdx.x >> 6;
  const int slot = blockIdx.x * 4 + wv;  // 0..63
  float a8[8], acc8[8];
#pragma unroll
  for (int j = 0; j < 8; ++j) {
    a8[j] = alpha[lane * 8 + j] * FSCALE;
    acc8[j] = 0.f;
  }
  for (int i = 0; i < 64; ++i) {
    int row = slot * 64 + i;
    const u16* qr = qk + (size_t)(b * SEQ + row) * NQK + lane * 8;
    short8 s = *(const short8*)qr;
    float q[8], t[8];
    float m = -1e30f;
#pragma unroll
    for (int j = 0; j < 8; ++j) {
      q[j] = bf2f((u16)s[j]);
      t[j] = q[j] * a8[j];
      m = fmaxf(m, t[j]);
    }
#pragma unroll
    for (int off = 32; off >= 1; off >>= 1) m = fmaxf(m, __shfl_xor(m, off));
    float sum = 0.f;
    float e[8];
#pragma unroll
    for (int j = 0; j < 8; ++j) {
      e[j] = __expf(t[j] - m);
      sum += e[j];
    }
#pragma unroll
    for (int off = 32; off >= 1; off >>= 1) sum += __shfl_xor(sum, off);
    float inv = 1.f / sum;
#pragma unroll
    for (int j = 0; j < 8; ++j) acc8[j] += q[j] * e[j] * inv;
  }
#pragma unroll
  for (int j = 0; j < 8; ++j) atomicAdd(&gq[b * 512 + lane * 8 + j], acc8[j]);
}

__global__ __launch_bounds__(256) void pool_beta(const u16* __restrict__ qk,
                                                 const float* __restrict__ beta,
                                                 const float* __restrict__ gq,
                                                 float* __restrict__ gk) {
  const int b = blockIdx.y;
  const int lane = threadIdx.x & 63, wv = threadIdx.x >> 6;
  const int slot = blockIdx.x * 4 + wv;
  float b8[8], g8[8], acc8[8];
#pragma unroll
  for (int j = 0; j < 8; ++j) {
    b8[j] = beta[lane * 8 + j] * FSCALE;
    g8[j] = gq[b * 512 + lane * 8 + j];
    acc8[j] = 0.f;
  }
  for (int i = 0; i < 64; ++i) {
    int row = slot * 64 + i;
    const u16* kr = qk + (size_t)(b * SEQ + row) * NQK + 512 + lane * 8;
    short8 s = *(const short8*)kr;
    float p[8], t[8];
    float m = -1e30f;
#pragma unroll
    for (int j = 0; j < 8; ++j) {
      p[j] = g8[j] * bf2f((u16)s[j]);
      t[j] = p[j] * b8[j];
      m = fmaxf(m, t[j]);
    }
#pragma unroll
    for (int off = 32; off >= 1; off >>= 1) m = fmaxf(m, __shfl_xor(m, off));
    float sum = 0.f;
    float e[8];
#pragma unroll
    for (int j = 0; j < 8; ++j) {
      e[j] = __expf(t[j] - m);
      sum += e[j];
    }
#pragma unroll
    for (int off = 32; off >= 1; off >>= 1) sum += __shfl_xor(sum, off);
    float inv = 1.f / sum;
#pragma unroll
    for (int j = 0; j < 8; ++j) acc8[j] += p[j] * e[j] * inv;
  }
#pragma unroll
  for (int j = 0; j < 8; ++j) atomicAdd(&gk[b * 512 + lane * 8 + j], acc8[j]);
}

// ---------------- Vgk[b][i][d] = bf16(Wv[i][d] * gk[b][d]) ----------------
__global__ void build_vgk(const float* __restrict__ Wv, const float* __restrict__ gk,
                          u16* __restrict__ Vgk) {
  int i = blockIdx.x, b = blockIdx.y;
  const float* gr = gk + b * 512;
  const float* wr = Wv + (size_t)i * 512;
  u16* o = Vgk + ((size_t)b * 512 + i) * 512;
  for (int d = threadIdx.x; d < 512; d += 256) o[d] = f2bf(wr[d] * gr[d]);
}

// ---------------- Wfin_b[e][i] = (Wrt @ Vgk_b^T)[e][i] + Wq[i][e], bf16 ----------------
__global__ __launch_bounds__(256) void gemm_wfin(const u16* __restrict__ Wrt,
                                                 const u16* __restrict__ Vgk,
                                                 const float* __restrict__ Wq,
                                                 u16* __restrict__ Wfin) {
  __shared__ u16 sA0[128 * 32], sB0[128 * 32], sA1[128 * 32], sB1[128 * 32];
  const int b = blockIdx.z;
  const int row0 = blockIdx.y * 128;  // e
  const int col0 = blockIdx.x * 128;  // i
  const u16* Bb = Vgk + (size_t)b * 512 * 512;
  u16* Cb = Wfin + (size_t)b * 512 * 512;

  floatx4 acc[4][4] = {};
  gemm_core<512, 512, 16>(Wrt, Bb, row0, col0, sA0, sB0, sA1, sB1, acc);

  const int lane = threadIdx.x & 63, wv = threadIdx.x >> 6;
  const int wm = (wv >> 1) * 64, wn = (wv & 1) * 64;
  const int ln = lane & 15, quad = lane >> 4;
#pragma unroll
  for (int i = 0; i < 4; ++i) {
#pragma unroll
    for (int r = 0; r < 4; ++r) {
      int grow = row0 + wm + i * 16 + quad * 4 + r;  // e
#pragma unroll
      for (int j = 0; j < 4; ++j) {
        int gcol = col0 + wn + ln + j * 16;  // i
        Cb[(size_t)grow * 512 + gcol] = f2bf(acc[i][j][r] + Wq[(size_t)gcol * 512 + grow]);
      }
    }
  }
}

// ---------------- out_b = xb_b @ Wfin_b^T (fp32 out) ----------------
__global__ __launch_bounds__(256) void gemm_final(const u16* __restrict__ xb,
                                                  const u16* __restrict__ Wfin,
                                                  float* __restrict__ out) {
  __shared__ u16 sA0[128 * 32], sB0[128 * 32], sA1[128 * 32], sB1[128 * 32];
  const int b = blockIdx.z;
  // per-z nwg = 4*32 = 128, divisible by 8 -> bijective chunked swizzle.
  int bid = blockIdx.y * 4 + blockIdx.x;
  int swz = (bid & 7) * 16 + (bid >> 3);
  const int row0 = (swz >> 2) * 128;  // 0..4095
  const int col0 = (swz & 3) * 128;   // 0..511
  const u16* Ab = xb + (size_t)b * SEQ * 512;
  const u16* Bb = Wfin + (size_t)b * 512 * 512;

  floatx4 acc[4][4] = {};
  gemm_core<512, 512, 16>(Ab, Bb, row0, col0, sA0, sB0, sA1, sB1, acc);

  const int lane = threadIdx.x & 63, wv = threadIdx.x >> 6;
  const int wm = (wv >> 1) * 64, wn = (wv & 1) * 64;
  const int ln = lane & 15, quad = lane >> 4;
#pragma unroll
  for (int i = 0; i < 4; ++i) {
#pragma unroll
    for (int r = 0; r < 4; ++r) {
      int grow = row0 + wm + i * 16 + quad * 4 + r;
      size_t orow = ((size_t)b * SEQ + grow) * 512;
#pragma unroll
      for (int j = 0; j < 4; ++j) {
        int gcol = col0 + wn + ln + j * 16;
        out[orow + gcol] = acc[i][j][r];
      }
    }
  }
}

// ---------------- launcher ----------------
extern "C" void kernel_launch(void* const* d_in, const int* in_sizes, int n_in,
                              void* d_out, int out_size, void* d_ws, size_t ws_size,
                              hipStream_t stream) {
  const float* x = (const float*)d_in[0];
  const float* Wq = (const float*)d_in[1];
  const float* Wk = (const float*)d_in[2];
  const float* Wv = (const float*)d_in[3];
  const float* Wr = (const float*)d_in[4];
  const float* alpha = (const float*)d_in[5];
  const float* beta = (const float*)d_in[6];
  float* out = (float*)d_out;

  char* ws = (char*)d_ws;
  // ws layout (bytes):
  //   xb   @ 0           134,217,728  (131072 x 512 bf16)
  //   qk   @ 134,217,728 268,435,456  (131072 x 1024 bf16; dead after pool_beta)
  //   Vgk  @ 134,217,728  16,777,216  (aliases dead qk)
  //   Wfin @ 151,994,944  16,777,216  (aliases dead qk)
  //   Wt   @ 402,653,184   1,048,576
  //   Wrt  @ 403,701,760     524,288
  //   gq   @ 404,226,048      65,536
  //   gk   @ 404,291,584      65,536
  u16* xb = (u16*)ws;
  u16* qk = (u16*)(ws + 134217728ull);
  u16* Vgk = (u16*)(ws + 134217728ull);
  u16* Wfin = (u16*)(ws + 151994944ull);
  u16* Wt = (u16*)(ws + 402653184ull);
  u16* Wrt = (u16*)(ws + 403701760ull);
  float* gq = (float*)(ws + 404226048ull);
  float* gk = gq + 16384;

  hipMemsetAsync(gq, 0, 131072, stream);  // gq+gk
  convert_x<<<32768, 256, 0, stream>>>(x, xb);
  prep_w<<<1536, 256, 0, stream>>>(Wq, Wk, Wr, Wt, Wrt);
  gemm_qk<<<dim3(8, 1024), 256, 0, stream>>>(xb, Wt, qk);
  pool_alpha<<<dim3(16, BATCH), 256, 0, stream>>>(qk, alpha, gq);
  pool_beta<<<dim3(16, BATCH), 256, 0, stream>>>(qk, beta, gq, gk);
  build_vgk<<<dim3(512, BATCH), 256, 0, stream>>>(Wv, gk, Vgk);
  gemm_wfin<<<dim3(4, 4, BATCH), 256, 0, stream>>>(Wrt, Vgk, Wq, Wfin);
  gemm_final<<<dim3(4, 32, BATCH), 256, 0, stream>>>(xb, Wfin, out);
}